// Round 8
// baseline (163.728 us; speedup 1.0000x reference)
//
#include <hip/hip_runtime.h>
#include <math.h>

#define BB 16
#define NN 2048
#define FF 64
#define SS 4
#define PP 22
#define OO 42
#define NREG 32             // all 2048/64 d2 values kept in VGPRs per lane
#define XBLK 512            // prep blocks: 64 rows each
#define WST 68              // LDS row stride (floats): 16B-aligned, non-mult-of-32

__device__ __forceinline__ float readfirstlane_f32(float v) {
    // value-preserving wave-uniform broadcast (builtin is int->int; must pass bits!)
    return __uint_as_float((unsigned)__builtin_amdgcn_readfirstlane((int)__float_as_uint(v)));
}

// canonical GCN wave64 inclusive scan via DPP: row_shr 1/2/4/8 (bound_ctrl -> OOB reads 0),
// then row_bcast:15 into rows 1,3 and row_bcast:31 into rows 2,3.
__device__ __forceinline__ int wave_scan_dpp(int x) {
    x += __builtin_amdgcn_update_dpp(0, x, 0x111, 0xf, 0xf, true);  // row_shr:1
    x += __builtin_amdgcn_update_dpp(0, x, 0x112, 0xf, 0xf, true);  // row_shr:2
    x += __builtin_amdgcn_update_dpp(0, x, 0x114, 0xf, 0xf, true);  // row_shr:4
    x += __builtin_amdgcn_update_dpp(0, x, 0x118, 0xf, 0xf, true);  // row_shr:8
    x += __builtin_amdgcn_update_dpp(0, x, 0x142, 0xa, 0xf, true);  // row_bcast:15
    x += __builtin_amdgcn_update_dpp(0, x, 0x143, 0xc, 0xf, true);  // row_bcast:31
    return x;
}
// float wave sum: same chain in float domain (0-bits = 0.0f additive identity)
__device__ __forceinline__ float wave_fsum_dpp(float x) {
    float t;
    t = __uint_as_float((unsigned)__builtin_amdgcn_update_dpp(0, (int)__float_as_uint(x), 0x111, 0xf, 0xf, true)); x += t;
    t = __uint_as_float((unsigned)__builtin_amdgcn_update_dpp(0, (int)__float_as_uint(x), 0x112, 0xf, 0xf, true)); x += t;
    t = __uint_as_float((unsigned)__builtin_amdgcn_update_dpp(0, (int)__float_as_uint(x), 0x114, 0xf, 0xf, true)); x += t;
    t = __uint_as_float((unsigned)__builtin_amdgcn_update_dpp(0, (int)__float_as_uint(x), 0x118, 0xf, 0xf, true)); x += t;
    t = __uint_as_float((unsigned)__builtin_amdgcn_update_dpp(0, (int)__float_as_uint(x), 0x142, 0xa, 0xf, true)); x += t;
    t = __uint_as_float((unsigned)__builtin_amdgcn_update_dpp(0, (int)__float_as_uint(x), 0x143, 0xc, 0xf, true)); x += t;
    return __uint_as_float((unsigned)__builtin_amdgcn_readlane((int)__float_as_uint(x), 63));
}

// ---- Kernel 1 (R4-proven, ~1-3us): unified 68-col GEMM, wave-per-64-rows ----
__global__ __launch_bounds__(256) void prep_kernel(
    const float* __restrict__ x, const float* __restrict__ Ws, const float* __restrict__ bs,
    const float* __restrict__ Wf, const float* __restrict__ bf,
    const float* __restrict__ Wo, const float* __restrict__ bo,
    float* __restrict__ coords, float* __restrict__ feats, float* __restrict__ xwo)
{
    __shared__ float wT[68 * WST];      // [o][k] transposed weights
    __shared__ float obufT[68 * WST];   // [o][row-lane] output tile
    __shared__ float bvec[68];

    const int lane = threadIdx.x & 63;
    const int wv   = threadIdx.x >> 6;          // 0..3
    const int r0   = blockIdx.x * 64;

    const float4* xr = (const float4*)(x + (size_t)(r0 + lane) * FF);
    float4 xv[16];
    #pragma unroll
    for (int k4 = 0; k4 < 16; k4++) xv[k4] = xr[k4];

    {
        int t = threadIdx.x;                    // Ws: 64x4 = 256 elems
        int k = t >> 2, s = t & 3;
        wT[s * WST + k] = Ws[t];
    }
    for (int t = threadIdx.x; t < 64 * PP; t += 256) {       // Wf: 1408
        int k = t / PP, c = t - k * PP;
        wT[(4 + c) * WST + k] = Wf[t];
    }
    for (int t = threadIdx.x; t < 64 * OO; t += 256) {       // Wo rows 0..63: 2688
        int k = t / OO, o = t - k * OO;
        wT[(26 + o) * WST + k] = Wo[t];
    }
    if (threadIdx.x < 68) {
        int o = threadIdx.x;
        bvec[o] = o < 4 ? bs[o] : (o < 26 ? bf[o - 4] : bo[o - 26]);
    }
    __syncthreads();

    for (int u = 0; u < 17; u++) {
        int o = wv * 17 + u;
        float a0 = bvec[o], a1 = 0.f, a2 = 0.f, a3 = 0.f;
        const float4* wrow = (const float4*)(wT + o * WST);
        #pragma unroll
        for (int k4 = 0; k4 < 16; k4++) {
            float4 w4 = wrow[k4];               // wave-uniform ds_read_b128 broadcast
            a0 = fmaf(xv[k4].x, w4.x, a0);
            a1 = fmaf(xv[k4].y, w4.y, a1);
            a2 = fmaf(xv[k4].z, w4.z, a2);
            a3 = fmaf(xv[k4].w, w4.w, a3);
        }
        obufT[o * WST + lane] = (a0 + a1) + (a2 + a3);
    }
    __syncthreads();

    if (threadIdx.x < 64) {
        int r = threadIdx.x;
        float4 cv = make_float4(obufT[0 * WST + r], obufT[1 * WST + r],
                                obufT[2 * WST + r], obufT[3 * WST + r]);
        *((float4*)(coords + (size_t)(r0 + r) * SS)) = cv;
    }
    for (int t = threadIdx.x; t < 32 * PP; t += 256) {       // feats 64x22
        int row = t / 11, c2 = t - row * 11;
        float2 v = make_float2(obufT[(4 + 2 * c2) * WST + row],
                               obufT[(4 + 2 * c2 + 1) * WST + row]);
        *((float2*)(feats + (size_t)r0 * PP + 2 * t)) = v;
    }
    for (int t = threadIdx.x; t < 32 * OO; t += 256) {       // xwo 64x42
        int row = t / 21, c2 = t - row * 21;
        float2 v = make_float2(obufT[(26 + 2 * c2) * WST + row],
                               obufT[(26 + 2 * c2 + 1) * WST + row]);
        *((float2*)(xwo + (size_t)r0 * OO + 2 * t)) = v;
    }
}

// ---- Kernel 2 (R22): R21 selection (proven) + restructured aggregation ----
// R21's agg was the exposed-latency chain: 2 groups x 22 lanes x ~20 serial iters of
// ds_read -> dependent scattered global load. Now 5 groups x 11 lanes x float2
// (55 lanes, ~8 iters: 2.5x shorter chain), selection packed as one u64
// selk = (exp(-d2) << 32) | j*PP (exp at selection time: no separate pass/barrier;
// pre-multiplied j*PP: no per-iter mul; one ds_read_b64 per neighbor). Partial
// max/sum reduced via small LDS buffer. Selection math byte-identical to R21.
__global__ __launch_bounds__(128, 4) void knn_out_kernel(
    const float* __restrict__ coords, const float* __restrict__ feats,
    const float* __restrict__ xwo, const float* __restrict__ Wo,
    const int* __restrict__ nnbr, float* __restrict__ out)
{
    const int lane = threadIdx.x & 63;
    const int w    = threadIdx.x >> 6;
    const int q    = blockIdx.x * 2 + w;       // 0..32767
    const int b    = q >> 11;
    const int i    = q & (NN - 1);

    int K = *nnbr; K = K < 2 ? 2 : (K > 64 ? 64 : K);

    __shared__ unsigned long long candk[2][64];   // (d2bits<<32)|j packed keys
    __shared__ unsigned long long selk[2][64];    // (expw bits<<32)|(j*PP)
    __shared__ float pbuf[2][220];                // [g][h][22] partials, g=0..4 h=max/mean
    __shared__ __align__(16) float urow[2][48];   // [max | mean], 44 used

    // prefetch the precomputed x-part of the output (overlaps the distance phase)
    float xw = 0.f;
    if (lane < OO) xw = xwo[(size_t)q * OO + lane];

    const float4* cb = (const float4*)(coords + (size_t)b * NN * SS);
    float4 qv = cb[i];
    const float qx = readfirstlane_f32(qv.x);
    const float qy = readfirstlane_f32(qv.y);
    const float qz = readfirstlane_f32(qv.z);
    const float qw = readfirstlane_f32(qv.w);

    // ---- distances: all 2048 kept in 32 VGPRs/lane; track per-lane min ----
    float d2r[NREG];
    float lmin = INFINITY;
    #pragma unroll 4
    for (int r = 0; r < NREG; r++) {
        float4 c = cb[r * 64 + lane];
        float d0 = qx - c.x, d1 = qy - c.y, d2 = qz - c.z, d3 = qw - c.w;
        float v = d0 * d0 + d1 * d1 + d2 * d2 + d3 * d3;
        d2r[r] = v;
        lmin = fminf(lmin, v);
    }

    // ---- t0: mean of per-lane minima ~ local scale (adapts to density) ----
    float t0 = wave_fsum_dpp(lmin) * (1.0f / 64.0f);
    if (!(t0 > 1e-30f)) t0 = 1e-30f;

    // ---- bracketed single-window search: count(hi) in [K, 64] (R21-proven) ----
    const float targetc = 0.5f * (float)(K + 64);          // 52 for K=40
    unsigned bLoU = 0u;              // invariant: count(< bLo) < K
    unsigned bHiU = 0x7F800000u;     // invariant: count(< bHi) > 64
    unsigned hiU  = __float_as_uint(t0 * __fsqrt_rn(targetc * (1.0f / 40.0f)));
    if (hiU <= bLoU) hiU = bLoU + 1u;
    if (hiU >= bHiU) hiU = bHiU - 1u;

    int ecand = 0, lcnt = 0, incl = 0;
    for (int att = 0; att < 32; att++) {
        float hi = __uint_as_float(hiU);
        lcnt = 0;
        #pragma unroll
        for (int r = 0; r < NREG; r++) lcnt += (d2r[r] < hi) ? 1 : 0;
        incl  = wave_scan_dpp(lcnt);                       // inclusive scan
        ecand = __builtin_amdgcn_readlane(incl, 63);       // exact wave count
        if (ecand >= K && ecand <= 64) break;

        unsigned prop;
        if (ecand < K) {
            bLoU = hiU;
            float denom = (float)(ecand < 2 ? 2 : ecand);
            float sc = __fsqrt_rn(targetc / denom);        // count ~ hi^2 power law
            sc = sc > 4.0f ? 4.0f : sc;
            prop = __float_as_uint(hi * sc);
        } else {                                           // ecand > 64
            bHiU = hiU;
            prop = __float_as_uint(hi * __fsqrt_rn(targetc / (float)ecand));
        }
        if (bHiU - bLoU <= 1u) break;                      // mass-tie pathological only
        if (att >= 3 || !(prop > bLoU && prop < bHiU))     // force bisection: converges
            prop = bLoU + ((bHiU - bLoU) >> 1);
        if (prop <= bLoU) prop = bLoU + 1u;
        if (prop >= bHiU) prop = bHiU - 1u;
        hiU = prop;
    }
    const float hi = __uint_as_float(hiU);
    if (ecand > 64) ecand = 64;      // unreachable for distinct d2; safety clamp

    // ---- collect: per-lane base from exclusive scan; sequential writes ----
    int b2 = incl - lcnt;
    #pragma unroll
    for (int r = 0; r < NREG; r++) {
        float v = d2r[r];
        if (v < hi) {
            if (b2 < 64)
                candk[w][b2] = ((unsigned long long)__float_as_uint(v) << 32) | (unsigned)(r * 64 + lane);
            b2++;
        }
    }
    __builtin_amdgcn_wave_barrier();

    // ---- rank candidates; keep K smallest (self = rank 0), skip self ----
    unsigned long long mykey = ~0ull;
    if (lane < ecand) mykey = candk[w][lane];
    int mr = 0;
    for (int u = 0; u < ecand; u++) {            // ds_read_b64 broadcast, conflict-free
        unsigned long long ku = candk[w][u];
        mr += (ku < mykey) ? 1 : 0;
    }
    int mj = (int)(mykey & 0xFFFFFFFFull);
    bool ps = (lane < ecand) & (mr < K) & (mj != i);
    unsigned long long ms = __ballot(ps);
    if (ps) {
        int slot = __popcll(ms & ((1ull << lane) - 1ull));
        float wt = __expf(-__uint_as_float((unsigned)(mykey >> 32)));
        selk[w][slot] = ((unsigned long long)__float_as_uint(wt) << 32) | (unsigned)(mj * PP);
    }
    int nsel = __popcll(ms);                     // expect K-1 = 39
    if (nsel > 64) nsel = 64;
    __builtin_amdgcn_wave_barrier();

    // ---- weighted max / mean: 5 m-groups x 11 lanes x 2 cols (55 lanes active) ----
    const int g  = lane / 11;                    // 0..5 (g==5: lanes 55-63 idle)
    const int cp = lane - g * 11;                // 0..10 -> cols 2cp, 2cp+1
    if (g < 5) {
        const float* fb2 = feats + (size_t)b * NN * PP + 2 * cp;
        float mx0 = -INFINITY, mx1 = -INFINITY, sm0 = 0.f, sm1 = 0.f;
        #pragma unroll 4
        for (int m = g; m < nsel; m += 5) {
            unsigned long long e = selk[w][m];   // one b64 read: {weight, j*PP}
            float wt = __uint_as_float((unsigned)(e >> 32));
            float2 f2 = *((const float2*)(fb2 + (unsigned)(e & 0xFFFFFFFFull)));
            float w0 = wt * f2.x, w1 = wt * f2.y;
            mx0 = fmaxf(mx0, w0); sm0 += w0;
            mx1 = fmaxf(mx1, w1); sm1 += w1;
        }
        // partials: pbuf[(g*2+h)*22 + c], h=0 max, h=1 sum
        *((float2*)&pbuf[w][(g * 2 + 0) * 22 + 2 * cp]) = make_float2(mx0, mx1);
        *((float2*)&pbuf[w][(g * 2 + 1) * 22 + 2 * cp]) = make_float2(sm0, sm1);
    }
    __builtin_amdgcn_wave_barrier();

    // reduce 5 groups -> urow: lanes 0-21 max, lanes 22-43 mean
    if (lane < 44) {
        int h = (lane >= PP) ? 1 : 0;
        int c = lane - h * PP;
        float v0 = pbuf[w][(0 * 2 + h) * 22 + c];
        float v1 = pbuf[w][(1 * 2 + h) * 22 + c];
        float v2 = pbuf[w][(2 * 2 + h) * 22 + c];
        float v3 = pbuf[w][(3 * 2 + h) * 22 + c];
        float v4 = pbuf[w][(4 * 2 + h) * 22 + c];
        float v;
        if (h == 0) v = fmaxf(fmaxf(fmaxf(v0, v1), fmaxf(v2, v3)), v4);
        else        v = ((v0 + v1) + (v2 + v3) + v4) * (1.0f / (float)(K - 1));
        urow[w][h * PP + c] = v;
    }
    __builtin_amdgcn_wave_barrier();

    // ---- epilogue: out[q][o] = tanh(xwo + [max|mean] . Wo[64:,o]), lanes 0-41 ----
    if (lane < OO) {
        float a0 = xw, a1 = 0.f, a2 = 0.f, a3 = 0.f;
        const float* wo = Wo + FF * OO + lane;   // rows 64..107, coalesced across lanes
        #pragma unroll
        for (int k4 = 0; k4 < (2 * PP) / 4; k4++) {
            float4 u = *((const float4*)&urow[w][k4 * 4]);   // ds_read_b128 broadcast
            a0 = fmaf(u.x, wo[(k4 * 4 + 0) * OO], a0);
            a1 = fmaf(u.y, wo[(k4 * 4 + 1) * OO], a1);
            a2 = fmaf(u.z, wo[(k4 * 4 + 2) * OO], a2);
            a3 = fmaf(u.w, wo[(k4 * 4 + 3) * OO], a3);
        }
        float acc = (a0 + a1) + (a2 + a3);
        float a = acc < -12.f ? -12.f : (acc > 12.f ? 12.f : acc);
        float e2 = __expf(2.f * a);
        out[(size_t)q * OO + lane] = (e2 - 1.f) / (e2 + 1.f);
    }
}

extern "C" void kernel_launch(void* const* d_in, const int* in_sizes, int n_in,
                              void* d_out, int out_size, void* d_ws, size_t ws_size,
                              hipStream_t stream) {
    const float* x  = (const float*)d_in[0];
    const float* Ws = (const float*)d_in[1];
    const float* bs = (const float*)d_in[2];
    const float* Wf = (const float*)d_in[3];
    const float* bf = (const float*)d_in[4];
    const float* Wo = (const float*)d_in[5];
    const float* bo = (const float*)d_in[6];
    const int*   nn = (const int*)d_in[7];
    float* out = (float*)d_out;

    float* coords = (float*)d_ws;                              // 16*2048*4  = 512 KB
    float* feats  = coords + (size_t)BB * NN * SS;             // 16*2048*22 = 2.75 MB
    float* xwo    = feats  + (size_t)BB * NN * PP;             // 32768*42   = 5.5 MB

    prep_kernel<<<XBLK, 256, 0, stream>>>(x, Ws, bs, Wf, bf, Wo, bo, coords, feats, xwo);
    knn_out_kernel<<<(BB * NN) / 2, 128, 0, stream>>>(coords, feats, xwo, Wo, nn, out);
}

// Round 9
// 162.976 us; speedup vs baseline: 1.0046x; 1.0046x over previous
//
#include <hip/hip_runtime.h>
#include <math.h>

#define BB 16
#define NN 2048
#define FF 64
#define SS 4
#define PP 22
#define OO 42
#define NREG 32             // all 2048/64 d2 values kept in VGPRs per lane
#define XBLK 512            // prep blocks: 64 rows each
#define WST 68              // LDS row stride (floats): 16B-aligned, non-mult-of-32

__device__ __forceinline__ float readfirstlane_f32(float v) {
    // value-preserving wave-uniform broadcast (builtin is int->int; must pass bits!)
    return __uint_as_float((unsigned)__builtin_amdgcn_readfirstlane((int)__float_as_uint(v)));
}

// canonical GCN wave64 inclusive scan via DPP: row_shr 1/2/4/8 (bound_ctrl -> OOB reads 0),
// then row_bcast:15 into rows 1,3 and row_bcast:31 into rows 2,3.
__device__ __forceinline__ int wave_scan_dpp(int x) {
    x += __builtin_amdgcn_update_dpp(0, x, 0x111, 0xf, 0xf, true);  // row_shr:1
    x += __builtin_amdgcn_update_dpp(0, x, 0x112, 0xf, 0xf, true);  // row_shr:2
    x += __builtin_amdgcn_update_dpp(0, x, 0x114, 0xf, 0xf, true);  // row_shr:4
    x += __builtin_amdgcn_update_dpp(0, x, 0x118, 0xf, 0xf, true);  // row_shr:8
    x += __builtin_amdgcn_update_dpp(0, x, 0x142, 0xa, 0xf, true);  // row_bcast:15
    x += __builtin_amdgcn_update_dpp(0, x, 0x143, 0xc, 0xf, true);  // row_bcast:31
    return x;
}
// float wave sum: same chain in float domain (0-bits = 0.0f additive identity)
__device__ __forceinline__ float wave_fsum_dpp(float x) {
    float t;
    t = __uint_as_float((unsigned)__builtin_amdgcn_update_dpp(0, (int)__float_as_uint(x), 0x111, 0xf, 0xf, true)); x += t;
    t = __uint_as_float((unsigned)__builtin_amdgcn_update_dpp(0, (int)__float_as_uint(x), 0x112, 0xf, 0xf, true)); x += t;
    t = __uint_as_float((unsigned)__builtin_amdgcn_update_dpp(0, (int)__float_as_uint(x), 0x114, 0xf, 0xf, true)); x += t;
    t = __uint_as_float((unsigned)__builtin_amdgcn_update_dpp(0, (int)__float_as_uint(x), 0x118, 0xf, 0xf, true)); x += t;
    t = __uint_as_float((unsigned)__builtin_amdgcn_update_dpp(0, (int)__float_as_uint(x), 0x142, 0xa, 0xf, true)); x += t;
    t = __uint_as_float((unsigned)__builtin_amdgcn_update_dpp(0, (int)__float_as_uint(x), 0x143, 0xc, 0xf, true)); x += t;
    return __uint_as_float((unsigned)__builtin_amdgcn_readlane((int)__float_as_uint(x), 63));
}

// ---- Kernel 1 (R4-proven, ~1-3us): unified 68-col GEMM, wave-per-64-rows ----
__global__ __launch_bounds__(256) void prep_kernel(
    const float* __restrict__ x, const float* __restrict__ Ws, const float* __restrict__ bs,
    const float* __restrict__ Wf, const float* __restrict__ bf,
    const float* __restrict__ Wo, const float* __restrict__ bo,
    float* __restrict__ coords, float* __restrict__ feats, float* __restrict__ xwo)
{
    __shared__ float wT[68 * WST];      // [o][k] transposed weights
    __shared__ float obufT[68 * WST];   // [o][row-lane] output tile
    __shared__ float bvec[68];

    const int lane = threadIdx.x & 63;
    const int wv   = threadIdx.x >> 6;          // 0..3
    const int r0   = blockIdx.x * 64;

    const float4* xr = (const float4*)(x + (size_t)(r0 + lane) * FF);
    float4 xv[16];
    #pragma unroll
    for (int k4 = 0; k4 < 16; k4++) xv[k4] = xr[k4];

    {
        int t = threadIdx.x;                    // Ws: 64x4 = 256 elems
        int k = t >> 2, s = t & 3;
        wT[s * WST + k] = Ws[t];
    }
    for (int t = threadIdx.x; t < 64 * PP; t += 256) {       // Wf: 1408
        int k = t / PP, c = t - k * PP;
        wT[(4 + c) * WST + k] = Wf[t];
    }
    for (int t = threadIdx.x; t < 64 * OO; t += 256) {       // Wo rows 0..63: 2688
        int k = t / OO, o = t - k * OO;
        wT[(26 + o) * WST + k] = Wo[t];
    }
    if (threadIdx.x < 68) {
        int o = threadIdx.x;
        bvec[o] = o < 4 ? bs[o] : (o < 26 ? bf[o - 4] : bo[o - 26]);
    }
    __syncthreads();

    for (int u = 0; u < 17; u++) {
        int o = wv * 17 + u;
        float a0 = bvec[o], a1 = 0.f, a2 = 0.f, a3 = 0.f;
        const float4* wrow = (const float4*)(wT + o * WST);
        #pragma unroll
        for (int k4 = 0; k4 < 16; k4++) {
            float4 w4 = wrow[k4];               // wave-uniform ds_read_b128 broadcast
            a0 = fmaf(xv[k4].x, w4.x, a0);
            a1 = fmaf(xv[k4].y, w4.y, a1);
            a2 = fmaf(xv[k4].z, w4.z, a2);
            a3 = fmaf(xv[k4].w, w4.w, a3);
        }
        obufT[o * WST + lane] = (a0 + a1) + (a2 + a3);
    }
    __syncthreads();

    if (threadIdx.x < 64) {
        int r = threadIdx.x;
        float4 cv = make_float4(obufT[0 * WST + r], obufT[1 * WST + r],
                                obufT[2 * WST + r], obufT[3 * WST + r]);
        *((float4*)(coords + (size_t)(r0 + r) * SS)) = cv;
    }
    for (int t = threadIdx.x; t < 32 * PP; t += 256) {       // feats 64x22
        int row = t / 11, c2 = t - row * 11;
        float2 v = make_float2(obufT[(4 + 2 * c2) * WST + row],
                               obufT[(4 + 2 * c2 + 1) * WST + row]);
        *((float2*)(feats + (size_t)r0 * PP + 2 * t)) = v;
    }
    for (int t = threadIdx.x; t < 32 * OO; t += 256) {       // xwo 64x42
        int row = t / 21, c2 = t - row * 21;
        float2 v = make_float2(obufT[(26 + 2 * c2) * WST + row],
                               obufT[(26 + 2 * c2 + 1) * WST + row]);
        *((float2*)(xwo + (size_t)r0 * OO + 2 * t)) = v;
    }
}

// ---- Kernel 2 (R23): R21 base (83.0us proven) + selk packing + pipelined rank ----
// R22's pbuf partial tile caused 330K bank conflicts (110 bank-accesses/instr) and a
// serial reduce tail -> reverted to R21's 2x22 agg. Kept from R22: (a) selection packs
// one u64 selk = (exp(-d2)<<32)|(j*PP) -> agg loop does ONE ds_read_b64/neighbor, no
// per-iter mul, no separate exp pass/barrier; (b) candk padded with ~0ull sentinels so
// the rank loop runs fixed round-of-4 with 4 independent ds_read_b64/iter (loads
// overlap instead of serializing on lgkmcnt). Selection math byte-identical to R21.
__global__ __launch_bounds__(128, 4) void knn_out_kernel(
    const float* __restrict__ coords, const float* __restrict__ feats,
    const float* __restrict__ xwo, const float* __restrict__ Wo,
    const int* __restrict__ nnbr, float* __restrict__ out)
{
    const int lane = threadIdx.x & 63;
    const int w    = threadIdx.x >> 6;
    const int q    = blockIdx.x * 2 + w;       // 0..32767
    const int b    = q >> 11;
    const int i    = q & (NN - 1);

    int K = *nnbr; K = K < 2 ? 2 : (K > 64 ? 64 : K);

    __shared__ unsigned long long candk[2][64];   // (d2bits<<32)|j packed keys
    __shared__ unsigned long long selk[2][64];    // (expw bits<<32)|(j*PP)
    __shared__ __align__(16) float urow[2][48];   // [max | mean], 44 used

    // prefetch the precomputed x-part of the output (overlaps the distance phase)
    float xw = 0.f;
    if (lane < OO) xw = xwo[(size_t)q * OO + lane];

    // sentinel-fill candk so the rank loop can run a fixed padded count
    candk[w][lane] = ~0ull;
    __builtin_amdgcn_wave_barrier();

    const float4* cb = (const float4*)(coords + (size_t)b * NN * SS);
    float4 qv = cb[i];
    const float qx = readfirstlane_f32(qv.x);
    const float qy = readfirstlane_f32(qv.y);
    const float qz = readfirstlane_f32(qv.z);
    const float qw = readfirstlane_f32(qv.w);

    // ---- distances: all 2048 kept in 32 VGPRs/lane; track per-lane min ----
    float d2r[NREG];
    float lmin = INFINITY;
    #pragma unroll 4
    for (int r = 0; r < NREG; r++) {
        float4 c = cb[r * 64 + lane];
        float d0 = qx - c.x, d1 = qy - c.y, d2 = qz - c.z, d3 = qw - c.w;
        float v = d0 * d0 + d1 * d1 + d2 * d2 + d3 * d3;
        d2r[r] = v;
        lmin = fminf(lmin, v);
    }

    // ---- t0: mean of per-lane minima ~ local scale (adapts to density) ----
    float t0 = wave_fsum_dpp(lmin) * (1.0f / 64.0f);
    if (!(t0 > 1e-30f)) t0 = 1e-30f;

    // ---- bracketed single-window search: count(hi) in [K, 64] (R21-proven) ----
    const float targetc = 0.5f * (float)(K + 64);          // 52 for K=40
    unsigned bLoU = 0u;              // invariant: count(< bLo) < K
    unsigned bHiU = 0x7F800000u;     // invariant: count(< bHi) > 64
    unsigned hiU  = __float_as_uint(t0 * __fsqrt_rn(targetc * (1.0f / 40.0f)));
    if (hiU <= bLoU) hiU = bLoU + 1u;
    if (hiU >= bHiU) hiU = bHiU - 1u;

    int ecand = 0, lcnt = 0, incl = 0;
    for (int att = 0; att < 32; att++) {
        float hi = __uint_as_float(hiU);
        lcnt = 0;
        #pragma unroll
        for (int r = 0; r < NREG; r++) lcnt += (d2r[r] < hi) ? 1 : 0;
        incl  = wave_scan_dpp(lcnt);                       // inclusive scan
        ecand = __builtin_amdgcn_readlane(incl, 63);       // exact wave count
        if (ecand >= K && ecand <= 64) break;

        unsigned prop;
        if (ecand < K) {
            bLoU = hiU;
            float denom = (float)(ecand < 2 ? 2 : ecand);
            float sc = __fsqrt_rn(targetc / denom);        // count ~ hi^2 power law
            sc = sc > 4.0f ? 4.0f : sc;
            prop = __float_as_uint(hi * sc);
        } else {                                           // ecand > 64
            bHiU = hiU;
            prop = __float_as_uint(hi * __fsqrt_rn(targetc / (float)ecand));
        }
        if (bHiU - bLoU <= 1u) break;                      // mass-tie pathological only
        if (att >= 3 || !(prop > bLoU && prop < bHiU))     // force bisection: converges
            prop = bLoU + ((bHiU - bLoU) >> 1);
        if (prop <= bLoU) prop = bLoU + 1u;
        if (prop >= bHiU) prop = bHiU - 1u;
        hiU = prop;
    }
    const float hi = __uint_as_float(hiU);
    if (ecand > 64) ecand = 64;      // unreachable for distinct d2; safety clamp

    // ---- collect: per-lane base from exclusive scan; sequential writes ----
    int b2 = incl - lcnt;
    #pragma unroll
    for (int r = 0; r < NREG; r++) {
        float v = d2r[r];
        if (v < hi) {
            if (b2 < 64)
                candk[w][b2] = ((unsigned long long)__float_as_uint(v) << 32) | (unsigned)(r * 64 + lane);
            b2++;
        }
    }
    __builtin_amdgcn_wave_barrier();

    // ---- rank candidates (round-of-4 pipelined reads); keep K smallest, skip self ----
    unsigned long long mykey = ~0ull;
    if (lane < ecand) mykey = candk[w][lane];
    int mr = 0;
    const int iters = (ecand + 3) & ~3;          // sentinels (~0ull) never rank below
    for (int u = 0; u < iters; u += 4) {
        unsigned long long k0 = candk[w][u];
        unsigned long long k1 = candk[w][u + 1];
        unsigned long long k2 = candk[w][u + 2];
        unsigned long long k3 = candk[w][u + 3];
        mr += ((k0 < mykey) ? 1 : 0) + ((k1 < mykey) ? 1 : 0)
            + ((k2 < mykey) ? 1 : 0) + ((k3 < mykey) ? 1 : 0);
    }
    int mj = (int)(mykey & 0xFFFFFFFFull);
    bool ps = (lane < ecand) & (mr < K) & (mj != i);
    unsigned long long ms = __ballot(ps);
    if (ps) {
        int slot = __popcll(ms & ((1ull << lane) - 1ull));
        float wt = __expf(-__uint_as_float((unsigned)(mykey >> 32)));
        selk[w][slot] = ((unsigned long long)__float_as_uint(wt) << 32) | (unsigned)(mj * PP);
    }
    int nsel = __popcll(ms);                     // expect K-1 = 39
    if (nsel > 64) nsel = 64;
    __builtin_amdgcn_wave_barrier();

    // ---- weighted max / mean: lanes 0-21 do even m, lanes 32-53 odd m (R21 shape) ----
    const int g = lane >> 5, c = lane & 31;
    const float* fbc = feats + (size_t)b * NN * PP + c;
    float mx = -INFINITY, sm = 0.f;
    if (c < PP) {
        #pragma unroll 8
        for (int m = g; m < nsel; m += 2) {
            unsigned long long e = selk[w][m];   // one b64 broadcast read: {wt, j*PP}
            float wt = __uint_as_float((unsigned)(e >> 32));
            float f  = fbc[(unsigned)(e & 0xFFFFFFFFull)];
            float wf = wt * f;
            mx = fmaxf(mx, wf); sm += wf;
        }
    }
    float mx2 = __shfl_xor(mx, 32, 64);
    float sm2 = __shfl_xor(sm, 32, 64);
    mx = fmaxf(mx, mx2); sm += sm2;
    if (g == 0 && c < PP) {
        urow[w][c]      = mx;
        urow[w][PP + c] = sm / (float)(K - 1);
    }
    __builtin_amdgcn_wave_barrier();

    // ---- epilogue: out[q][o] = tanh(xwo + [max|mean] . Wo[64:,o]), lanes 0-41 ----
    if (lane < OO) {
        float a0 = xw, a1 = 0.f, a2 = 0.f, a3 = 0.f;
        const float* wo = Wo + FF * OO + lane;   // rows 64..107, coalesced across lanes
        #pragma unroll
        for (int k4 = 0; k4 < (2 * PP) / 4; k4++) {
            float4 u = *((const float4*)&urow[w][k4 * 4]);   // ds_read_b128 broadcast
            a0 = fmaf(u.x, wo[(k4 * 4 + 0) * OO], a0);
            a1 = fmaf(u.y, wo[(k4 * 4 + 1) * OO], a1);
            a2 = fmaf(u.z, wo[(k4 * 4 + 2) * OO], a2);
            a3 = fmaf(u.w, wo[(k4 * 4 + 3) * OO], a3);
        }
        float acc = (a0 + a1) + (a2 + a3);
        float a = acc < -12.f ? -12.f : (acc > 12.f ? 12.f : acc);
        float e2 = __expf(2.f * a);
        out[(size_t)q * OO + lane] = (e2 - 1.f) / (e2 + 1.f);
    }
}

extern "C" void kernel_launch(void* const* d_in, const int* in_sizes, int n_in,
                              void* d_out, int out_size, void* d_ws, size_t ws_size,
                              hipStream_t stream) {
    const float* x  = (const float*)d_in[0];
    const float* Ws = (const float*)d_in[1];
    const float* bs = (const float*)d_in[2];
    const float* bf_ = (const float*)d_in[4];
    const float* Wf = (const float*)d_in[3];
    const float* Wo = (const float*)d_in[5];
    const float* bo = (const float*)d_in[6];
    const int*   nn = (const int*)d_in[7];
    float* out = (float*)d_out;

    float* coords = (float*)d_ws;                              // 16*2048*4  = 512 KB
    float* feats  = coords + (size_t)BB * NN * SS;             // 16*2048*22 = 2.75 MB
    float* xwo    = feats  + (size_t)BB * NN * PP;             // 32768*42   = 5.5 MB

    prep_kernel<<<XBLK, 256, 0, stream>>>(x, Ws, bs, Wf, bf_, Wo, bo, coords, feats, xwo);
    knn_out_kernel<<<(BB * NN) / 2, 128, 0, stream>>>(coords, feats, xwo, Wo, nn, out);
}

// Round 10
// 160.867 us; speedup vs baseline: 1.0178x; 1.0131x over previous
//
#include <hip/hip_runtime.h>
#include <math.h>

#define BB 16
#define NN 2048
#define FF 64
#define SS 4
#define PP 22
#define OO 42
#define NREG 32             // all 2048/64 d2 values kept in VGPRs per lane
#define XBLK 512            // prep blocks: 64 rows each
#define WST 68              // LDS row stride (floats): 16B-aligned, non-mult-of-32

__device__ __forceinline__ float readfirstlane_f32(float v) {
    // value-preserving wave-uniform broadcast (builtin is int->int; must pass bits!)
    return __uint_as_float((unsigned)__builtin_amdgcn_readfirstlane((int)__float_as_uint(v)));
}

// canonical GCN wave64 inclusive scan via DPP: row_shr 1/2/4/8 (bound_ctrl -> OOB reads 0),
// then row_bcast:15 into rows 1,3 and row_bcast:31 into rows 2,3.
__device__ __forceinline__ int wave_scan_dpp(int x) {
    x += __builtin_amdgcn_update_dpp(0, x, 0x111, 0xf, 0xf, true);  // row_shr:1
    x += __builtin_amdgcn_update_dpp(0, x, 0x112, 0xf, 0xf, true);  // row_shr:2
    x += __builtin_amdgcn_update_dpp(0, x, 0x114, 0xf, 0xf, true);  // row_shr:4
    x += __builtin_amdgcn_update_dpp(0, x, 0x118, 0xf, 0xf, true);  // row_shr:8
    x += __builtin_amdgcn_update_dpp(0, x, 0x142, 0xa, 0xf, true);  // row_bcast:15
    x += __builtin_amdgcn_update_dpp(0, x, 0x143, 0xc, 0xf, true);  // row_bcast:31
    return x;
}
// float wave sum: same chain in float domain (0-bits = 0.0f additive identity)
__device__ __forceinline__ float wave_fsum_dpp(float x) {
    float t;
    t = __uint_as_float((unsigned)__builtin_amdgcn_update_dpp(0, (int)__float_as_uint(x), 0x111, 0xf, 0xf, true)); x += t;
    t = __uint_as_float((unsigned)__builtin_amdgcn_update_dpp(0, (int)__float_as_uint(x), 0x112, 0xf, 0xf, true)); x += t;
    t = __uint_as_float((unsigned)__builtin_amdgcn_update_dpp(0, (int)__float_as_uint(x), 0x114, 0xf, 0xf, true)); x += t;
    t = __uint_as_float((unsigned)__builtin_amdgcn_update_dpp(0, (int)__float_as_uint(x), 0x118, 0xf, 0xf, true)); x += t;
    t = __uint_as_float((unsigned)__builtin_amdgcn_update_dpp(0, (int)__float_as_uint(x), 0x142, 0xa, 0xf, true)); x += t;
    t = __uint_as_float((unsigned)__builtin_amdgcn_update_dpp(0, (int)__float_as_uint(x), 0x143, 0xc, 0xf, true)); x += t;
    return __uint_as_float((unsigned)__builtin_amdgcn_readlane((int)__float_as_uint(x), 63));
}

// ---- Kernel 1 (R4-proven, ~1-3us): unified 68-col GEMM, wave-per-64-rows ----
__global__ __launch_bounds__(256) void prep_kernel(
    const float* __restrict__ x, const float* __restrict__ Ws, const float* __restrict__ bs,
    const float* __restrict__ Wf, const float* __restrict__ bf,
    const float* __restrict__ Wo, const float* __restrict__ bo,
    float* __restrict__ coords, float* __restrict__ feats, float* __restrict__ xwo)
{
    __shared__ float wT[68 * WST];      // [o][k] transposed weights
    __shared__ float obufT[68 * WST];   // [o][row-lane] output tile
    __shared__ float bvec[68];

    const int lane = threadIdx.x & 63;
    const int wv   = threadIdx.x >> 6;          // 0..3
    const int r0   = blockIdx.x * 64;

    const float4* xr = (const float4*)(x + (size_t)(r0 + lane) * FF);
    float4 xv[16];
    #pragma unroll
    for (int k4 = 0; k4 < 16; k4++) xv[k4] = xr[k4];

    {
        int t = threadIdx.x;                    // Ws: 64x4 = 256 elems
        int k = t >> 2, s = t & 3;
        wT[s * WST + k] = Ws[t];
    }
    for (int t = threadIdx.x; t < 64 * PP; t += 256) {       // Wf: 1408
        int k = t / PP, c = t - k * PP;
        wT[(4 + c) * WST + k] = Wf[t];
    }
    for (int t = threadIdx.x; t < 64 * OO; t += 256) {       // Wo rows 0..63: 2688
        int k = t / OO, o = t - k * OO;
        wT[(26 + o) * WST + k] = Wo[t];
    }
    if (threadIdx.x < 68) {
        int o = threadIdx.x;
        bvec[o] = o < 4 ? bs[o] : (o < 26 ? bf[o - 4] : bo[o - 26]);
    }
    __syncthreads();

    for (int u = 0; u < 17; u++) {
        int o = wv * 17 + u;
        float a0 = bvec[o], a1 = 0.f, a2 = 0.f, a3 = 0.f;
        const float4* wrow = (const float4*)(wT + o * WST);
        #pragma unroll
        for (int k4 = 0; k4 < 16; k4++) {
            float4 w4 = wrow[k4];               // wave-uniform ds_read_b128 broadcast
            a0 = fmaf(xv[k4].x, w4.x, a0);
            a1 = fmaf(xv[k4].y, w4.y, a1);
            a2 = fmaf(xv[k4].z, w4.z, a2);
            a3 = fmaf(xv[k4].w, w4.w, a3);
        }
        obufT[o * WST + lane] = (a0 + a1) + (a2 + a3);
    }
    __syncthreads();

    if (threadIdx.x < 64) {
        int r = threadIdx.x;
        float4 cv = make_float4(obufT[0 * WST + r], obufT[1 * WST + r],
                                obufT[2 * WST + r], obufT[3 * WST + r]);
        *((float4*)(coords + (size_t)(r0 + r) * SS)) = cv;
    }
    for (int t = threadIdx.x; t < 32 * PP; t += 256) {       // feats 64x22
        int row = t / 11, c2 = t - row * 11;
        float2 v = make_float2(obufT[(4 + 2 * c2) * WST + row],
                               obufT[(4 + 2 * c2 + 1) * WST + row]);
        *((float2*)(feats + (size_t)r0 * PP + 2 * t)) = v;
    }
    for (int t = threadIdx.x; t < 32 * OO; t += 256) {       // xwo 64x42
        int row = t / 21, c2 = t - row * 21;
        float2 v = make_float2(obufT[(26 + 2 * c2) * WST + row],
                               obufT[(26 + 2 * c2 + 1) * WST + row]);
        *((float2*)(xwo + (size_t)r0 * OO + 2 * t)) = v;
    }
}

// ---- Kernel 2 (R24): R23 body (82.0us proven) at WG=256 / 4 waves per block ----
// Occupancy has been pinned at 75% (24/32 waves per CU) for all rounds despite
// VGPR=32 / LDS=2.5KB imposing no limit -> suspected per-CU workgroup-slot cap
// (needed 16 co-resident 128-thread WGs; now only 8 of 256 threads). Waves remain
// fully independent: per-wave LDS slices (w = tid>>6), wave_barrier only, no
// __syncthreads. All selection/agg/epilogue code byte-identical to R23.
__global__ __launch_bounds__(256, 2) void knn_out_kernel(
    const float* __restrict__ coords, const float* __restrict__ feats,
    const float* __restrict__ xwo, const float* __restrict__ Wo,
    const int* __restrict__ nnbr, float* __restrict__ out)
{
    const int lane = threadIdx.x & 63;
    const int w    = threadIdx.x >> 6;         // 0..3
    const int q    = blockIdx.x * 4 + w;       // 0..32767
    const int b    = q >> 11;
    const int i    = q & (NN - 1);

    int K = *nnbr; K = K < 2 ? 2 : (K > 64 ? 64 : K);

    __shared__ unsigned long long candk[4][64];   // (d2bits<<32)|j packed keys
    __shared__ unsigned long long selk[4][64];    // (expw bits<<32)|(j*PP)
    __shared__ __align__(16) float urow[4][48];   // [max | mean], 44 used

    // prefetch the precomputed x-part of the output (overlaps the distance phase)
    float xw = 0.f;
    if (lane < OO) xw = xwo[(size_t)q * OO + lane];

    // sentinel-fill candk so the rank loop can run a fixed padded count
    candk[w][lane] = ~0ull;
    __builtin_amdgcn_wave_barrier();

    const float4* cb = (const float4*)(coords + (size_t)b * NN * SS);
    float4 qv = cb[i];
    const float qx = readfirstlane_f32(qv.x);
    const float qy = readfirstlane_f32(qv.y);
    const float qz = readfirstlane_f32(qv.z);
    const float qw = readfirstlane_f32(qv.w);

    // ---- distances: all 2048 kept in 32 VGPRs/lane; track per-lane min ----
    float d2r[NREG];
    float lmin = INFINITY;
    #pragma unroll 4
    for (int r = 0; r < NREG; r++) {
        float4 c = cb[r * 64 + lane];
        float d0 = qx - c.x, d1 = qy - c.y, d2 = qz - c.z, d3 = qw - c.w;
        float v = d0 * d0 + d1 * d1 + d2 * d2 + d3 * d3;
        d2r[r] = v;
        lmin = fminf(lmin, v);
    }

    // ---- t0: mean of per-lane minima ~ local scale (adapts to density) ----
    float t0 = wave_fsum_dpp(lmin) * (1.0f / 64.0f);
    if (!(t0 > 1e-30f)) t0 = 1e-30f;

    // ---- bracketed single-window search: count(hi) in [K, 64] (R21-proven) ----
    const float targetc = 0.5f * (float)(K + 64);          // 52 for K=40
    unsigned bLoU = 0u;              // invariant: count(< bLo) < K
    unsigned bHiU = 0x7F800000u;     // invariant: count(< bHi) > 64
    unsigned hiU  = __float_as_uint(t0 * __fsqrt_rn(targetc * (1.0f / 40.0f)));
    if (hiU <= bLoU) hiU = bLoU + 1u;
    if (hiU >= bHiU) hiU = bHiU - 1u;

    int ecand = 0, lcnt = 0, incl = 0;
    for (int att = 0; att < 32; att++) {
        float hi = __uint_as_float(hiU);
        lcnt = 0;
        #pragma unroll
        for (int r = 0; r < NREG; r++) lcnt += (d2r[r] < hi) ? 1 : 0;
        incl  = wave_scan_dpp(lcnt);                       // inclusive scan
        ecand = __builtin_amdgcn_readlane(incl, 63);       // exact wave count
        if (ecand >= K && ecand <= 64) break;

        unsigned prop;
        if (ecand < K) {
            bLoU = hiU;
            float denom = (float)(ecand < 2 ? 2 : ecand);
            float sc = __fsqrt_rn(targetc / denom);        // count ~ hi^2 power law
            sc = sc > 4.0f ? 4.0f : sc;
            prop = __float_as_uint(hi * sc);
        } else {                                           // ecand > 64
            bHiU = hiU;
            prop = __float_as_uint(hi * __fsqrt_rn(targetc / (float)ecand));
        }
        if (bHiU - bLoU <= 1u) break;                      // mass-tie pathological only
        if (att >= 3 || !(prop > bLoU && prop < bHiU))     // force bisection: converges
            prop = bLoU + ((bHiU - bLoU) >> 1);
        if (prop <= bLoU) prop = bLoU + 1u;
        if (prop >= bHiU) prop = bHiU - 1u;
        hiU = prop;
    }
    const float hi = __uint_as_float(hiU);
    if (ecand > 64) ecand = 64;      // unreachable for distinct d2; safety clamp

    // ---- collect: per-lane base from exclusive scan; sequential writes ----
    int b2 = incl - lcnt;
    #pragma unroll
    for (int r = 0; r < NREG; r++) {
        float v = d2r[r];
        if (v < hi) {
            if (b2 < 64)
                candk[w][b2] = ((unsigned long long)__float_as_uint(v) << 32) | (unsigned)(r * 64 + lane);
            b2++;
        }
    }
    __builtin_amdgcn_wave_barrier();

    // ---- rank candidates (round-of-4 pipelined reads); keep K smallest, skip self ----
    unsigned long long mykey = ~0ull;
    if (lane < ecand) mykey = candk[w][lane];
    int mr = 0;
    const int iters = (ecand + 3) & ~3;          // sentinels (~0ull) never rank below
    for (int u = 0; u < iters; u += 4) {
        unsigned long long k0 = candk[w][u];
        unsigned long long k1 = candk[w][u + 1];
        unsigned long long k2 = candk[w][u + 2];
        unsigned long long k3 = candk[w][u + 3];
        mr += ((k0 < mykey) ? 1 : 0) + ((k1 < mykey) ? 1 : 0)
            + ((k2 < mykey) ? 1 : 0) + ((k3 < mykey) ? 1 : 0);
    }
    int mj = (int)(mykey & 0xFFFFFFFFull);
    bool ps = (lane < ecand) & (mr < K) & (mj != i);
    unsigned long long ms = __ballot(ps);
    if (ps) {
        int slot = __popcll(ms & ((1ull << lane) - 1ull));
        float wt = __expf(-__uint_as_float((unsigned)(mykey >> 32)));
        selk[w][slot] = ((unsigned long long)__float_as_uint(wt) << 32) | (unsigned)(mj * PP);
    }
    int nsel = __popcll(ms);                     // expect K-1 = 39
    if (nsel > 64) nsel = 64;
    __builtin_amdgcn_wave_barrier();

    // ---- weighted max / mean: lanes 0-21 do even m, lanes 32-53 odd m ----
    const int g = lane >> 5, c = lane & 31;
    const float* fbc = feats + (size_t)b * NN * PP + c;
    float mx = -INFINITY, sm = 0.f;
    if (c < PP) {
        #pragma unroll 8
        for (int m = g; m < nsel; m += 2) {
            unsigned long long e = selk[w][m];   // one b64 broadcast read: {wt, j*PP}
            float wt = __uint_as_float((unsigned)(e >> 32));
            float f  = fbc[(unsigned)(e & 0xFFFFFFFFull)];
            float wf = wt * f;
            mx = fmaxf(mx, wf); sm += wf;
        }
    }
    float mx2 = __shfl_xor(mx, 32, 64);
    float sm2 = __shfl_xor(sm, 32, 64);
    mx = fmaxf(mx, mx2); sm += sm2;
    if (g == 0 && c < PP) {
        urow[w][c]      = mx;
        urow[w][PP + c] = sm / (float)(K - 1);
    }
    __builtin_amdgcn_wave_barrier();

    // ---- epilogue: out[q][o] = tanh(xwo + [max|mean] . Wo[64:,o]), lanes 0-41 ----
    if (lane < OO) {
        float a0 = xw, a1 = 0.f, a2 = 0.f, a3 = 0.f;
        const float* wo = Wo + FF * OO + lane;   // rows 64..107, coalesced across lanes
        #pragma unroll
        for (int k4 = 0; k4 < (2 * PP) / 4; k4++) {
            float4 u = *((const float4*)&urow[w][k4 * 4]);   // ds_read_b128 broadcast
            a0 = fmaf(u.x, wo[(k4 * 4 + 0) * OO], a0);
            a1 = fmaf(u.y, wo[(k4 * 4 + 1) * OO], a1);
            a2 = fmaf(u.z, wo[(k4 * 4 + 2) * OO], a2);
            a3 = fmaf(u.w, wo[(k4 * 4 + 3) * OO], a3);
        }
        float acc = (a0 + a1) + (a2 + a3);
        float a = acc < -12.f ? -12.f : (acc > 12.f ? 12.f : acc);
        float e2 = __expf(2.f * a);
        out[(size_t)q * OO + lane] = (e2 - 1.f) / (e2 + 1.f);
    }
}

extern "C" void kernel_launch(void* const* d_in, const int* in_sizes, int n_in,
                              void* d_out, int out_size, void* d_ws, size_t ws_size,
                              hipStream_t stream) {
    const float* x  = (const float*)d_in[0];
    const float* Ws = (const float*)d_in[1];
    const float* bs = (const float*)d_in[2];
    const float* Wf = (const float*)d_in[3];
    const float* bf = (const float*)d_in[4];
    const float* Wo = (const float*)d_in[5];
    const float* bo = (const float*)d_in[6];
    const int*   nn = (const int*)d_in[7];
    float* out = (float*)d_out;

    float* coords = (float*)d_ws;                              // 16*2048*4  = 512 KB
    float* feats  = coords + (size_t)BB * NN * SS;             // 16*2048*22 = 2.75 MB
    float* xwo    = feats  + (size_t)BB * NN * PP;             // 32768*42   = 5.5 MB

    prep_kernel<<<XBLK, 256, 0, stream>>>(x, Ws, bs, Wf, bf, Wo, bo, coords, feats, xwo);
    knn_out_kernel<<<(BB * NN) / 4, 256, 0, stream>>>(coords, feats, xwo, Wo, nn, out);
}